// Round 5
// baseline (342.515 us; speedup 1.0000x reference)
//
#include <hip/hip_runtime.h>
#include <math.h>

#define NN 32000
#define PP 1000
#define KK 40
#define INC 64
#define DD 32
#define EPSV 1e-5

// ws BYTE offsets. Total ~21.6 MB.
// h64 TRANSPOSED [32][NN] f64; sT [3][NN] f64; F32 row-major [NN][32];
// aggr [NN][64] f32; P1 [500][64] f64; P2 [250][64] f64
#define OB_H64 0UL
#define OB_S64 8192000UL
#define OB_F32 8960000UL
#define OB_A32 13056000UL
#define OB_P1  21248000UL
#define OB_P2  21504000UL

#define NP1 500
#define NP2 250

__device__ __forceinline__ double elud(double v){ return v > 0.0 ? v : expm1(v); }
__device__ __forceinline__ float eluf(float v){ return v > 0.f ? v : expm1f(v); }

// pre-MLP in f64, 2 threads per node (each owns 16 output channels)
__global__ __launch_bounds__(128) void k_pre(const float* __restrict__ x,
    const float* __restrict__ w1, const float* __restrict__ b1,
    const float* __restrict__ w2, const float* __restrict__ b2,
    char* __restrict__ ws)
{
  __shared__ double lw1[INC*DD];   // 16 KB
  __shared__ double lw2[DD*DD];    // 8 KB
  __shared__ float  lx[64*65];     // 16.6 KB, padded stride 65 (bank-conflict-free)
  __shared__ double lb1[DD], lb2[DD];
  __shared__ double wpart[2][64];
  int tid = threadIdx.x;
  int nodeBase = blockIdx.x * 64;
  for (int i = tid; i < INC*DD; i += 128) lw1[i] = (double)w1[i];
  for (int i = tid; i < DD*DD; i += 128) lw2[i] = (double)w2[i];
  if (tid < DD){ lb1[tid] = (double)b1[tid]; lb2[tid] = (double)b2[tid]; }
  for (int i = tid; i < 64*64; i += 128)
    lx[(i >> 6)*65 + (i & 63)] = x[(size_t)nodeBase*INC + i];
  __syncthreads();

  int nl = tid >> 1, half = tid & 1;
  int node = nodeBase + nl;
  double acc[16];
#pragma unroll
  for (int c = 0; c < 16; ++c) acc[c] = lb1[half*16 + c];
#pragma unroll 4
  for (int k = 0; k < INC; ++k){
    double xv = (double)lx[nl*65 + k];
#pragma unroll
    for (int c = 0; c < 16; ++c) acc[c] = fma(xv, lw1[k*DD + half*16 + c], acc[c]);
  }
  double h1o[16];
#pragma unroll
  for (int c = 0; c < 16; ++c) h1o[c] = elud(acc[c]);
  // exchange with partner thread (lane^1) to build full h1[32]
  double h1f[DD];
#pragma unroll
  for (int i = 0; i < 16; ++i){
    double p = __shfl_xor(h1o[i], 1);
    h1f[i]      = half ? p : h1o[i];
    h1f[16 + i] = half ? h1o[i] : p;
  }
#pragma unroll
  for (int c = 0; c < 16; ++c) acc[c] = lb2[half*16 + c];
#pragma unroll 4
  for (int k = 0; k < DD; ++k){
    double hk = h1f[k];
#pragma unroll
    for (int c = 0; c < 16; ++c) acc[c] = fma(hk, lw2[k*DD + half*16 + c], acc[c]);
  }
  double h2[16];
#pragma unroll
  for (int c = 0; c < 16; ++c) h2[c] = elud(acc[c]);
  double* hT = (double*)(ws + OB_H64);
#pragma unroll
  for (int c = 0; c < 16; ++c) hT[(size_t)(half*16 + c)*NN + node] = h2[c];

  // partial stats: parity butterfly (even lanes ch0-15, odd lanes ch16-31)
  double s[16], q[16];
#pragma unroll
  for (int i = 0; i < 16; ++i){ s[i] = h2[i]; q[i] = h2[i]*h2[i]; }
#pragma unroll
  for (int o = 2; o <= 32; o <<= 1){
#pragma unroll
    for (int i = 0; i < 16; ++i){ s[i] += __shfl_xor(s[i], o); q[i] += __shfl_xor(q[i], o); }
  }
  int lane = tid & 63, wid = tid >> 6;
  if (lane < 2){
#pragma unroll
    for (int i = 0; i < 16; ++i){
      wpart[wid][lane*16 + i]      = s[i];
      wpart[wid][32 + lane*16 + i] = q[i];
    }
  }
  __syncthreads();
  if (tid < 64)
    ((double*)(ws + OB_P1))[blockIdx.x*64 + tid] = wpart[0][tid] + wpart[1][tid];
}

// BN1 finalize (redundant per block) + BN apply (f64) + s (f64) + feat (f32)
__global__ __launch_bounds__(128) void k_sfeat(
    const float* __restrict__ sw, const float* __restrict__ sb,
    const float* __restrict__ hw, const float* __restrict__ hb,
    const float* __restrict__ g, const float* __restrict__ b,
    char* __restrict__ ws)
{
  __shared__ double sums[2][64], ltot[64], lstat[64];
  __shared__ double lsw[DD*3], lsb[3], lg[DD], lbb[DD];
  __shared__ float lhw[DD*DD], lhb[DD];
  int tid = threadIdx.x;
  // finalize stats from 500 partial rows
  {
    const double* P1 = (const double*)(ws + OB_P1);
    int comp = tid & 63, grp = tid >> 6;
    double a = 0.0;
    for (int bb = grp; bb < NP1; bb += 2) a += P1[bb*64 + comp];
    sums[grp][comp] = a;
  }
  for (int i = tid; i < DD*3; i += 128) lsw[i] = (double)sw[i];
  for (int i = tid; i < DD*DD; i += 128) lhw[i] = hw[i];
  if (tid < 3) lsb[tid] = (double)sb[tid];
  if (tid < DD){ lhb[tid] = hb[tid]; lg[tid] = (double)g[tid]; lbb[tid] = (double)b[tid]; }
  __syncthreads();
  if (tid < 64) ltot[tid] = sums[0][tid] + sums[1][tid];
  __syncthreads();
  if (tid < 32){
    double m = ltot[tid] / (double)NN;
    double qq = ltot[32+tid] / (double)NN;
    lstat[tid] = m;
    lstat[32+tid] = 1.0 / sqrt(qq - m*m + EPSV);
  }
  __syncthreads();

  int node = blockIdx.x*128 + tid;
  double* hT = (double*)(ws + OB_H64);
  double hbn[DD];
#pragma unroll 4
  for (int c = 0; c < DD; ++c){
    double xv = hT[(size_t)c*NN + node];
    hbn[c] = (xv - lstat[c]) * lstat[32+c] * lg[c] + lbb[c];
  }
#pragma unroll 4
  for (int c = 0; c < DD; ++c) hT[(size_t)c*NN + node] = hbn[c];
  double s0 = lsb[0], s1 = lsb[1], s2 = lsb[2];
#pragma unroll
  for (int k = 0; k < DD; ++k){
    s0 = fma(hbn[k], lsw[k*3+0], s0);
    s1 = fma(hbn[k], lsw[k*3+1], s1);
    s2 = fma(hbn[k], lsw[k*3+2], s2);
  }
  double* sT = (double*)(ws + OB_S64);
  sT[node] = s0; sT[NN + node] = s1; sT[2*NN + node] = s2;
  float hv[DD];
#pragma unroll
  for (int c = 0; c < DD; ++c) hv[c] = (float)hbn[c];
  float f[DD];
#pragma unroll
  for (int c = 0; c < DD; ++c) f[c] = lhb[c];
#pragma unroll 4
  for (int k = 0; k < DD; ++k){
    float hk = hv[k];
#pragma unroll
    for (int c = 0; c < DD; ++c) f[c] = fmaf(hk, lhw[k*DD+c], f[c]);
  }
  float* frow = (float*)(ws + OB_F32) + (size_t)node*DD;
#pragma unroll
  for (int i = 0; i < DD; ++i) frow[i] = f[i];
}

// one wave per node. Event s-coords staged in LDS (SoA). d2 f64 identical to
// prior rounds. Selection: clamped binary search on u32 high words
// (lo = global min, hi = max-over-lanes of lane-min: valid bracket since each
// lane holds >=1 key <= its min => count(<=hi) >= 64 >= KK).
__global__ __launch_bounds__(256) void k_knn(char* __restrict__ ws)
{
  __shared__ double lsx[PP], lsy[PP], lsz[PP];   // 24 KB
  __shared__ int   lds_j[4][48];
  __shared__ float lds_w[4][48];
  const double* sT = (const double*)(ws + OB_S64);
  const float*  fp = (const float*)(ws + OB_F32);
  float* ap = (float*)(ws + OB_A32);
  int tid = threadIdx.x;
  int e = blockIdx.x / 250;
  int base = e * PP;
  for (int i = tid; i < PP; i += 256){
    lsx[i] = sT[base + i];
    lsy[i] = sT[NN + base + i];
    lsz[i] = sT[2*NN + base + i];
  }
  __syncthreads();
  int lane = tid & 63, wid = tid >> 6;
  int n = blockIdx.x * 4 + wid;
  int nl = n - base;
  double sx = lsx[nl], sy = lsy[nl], sz = lsz[nl];
  double d2v[16];
  unsigned hi32[16];
#pragma unroll
  for (int t = 0; t < 16; ++t){
    int j = lane + 64*t;
    double d2 = __builtin_inf();
    if (j < PP){
      double dx = lsx[j]-sx, dy = lsy[j]-sy, dz = lsz[j]-sz;
      d2 = (dx*dx + dy*dy) + dz*dz;   // np summation order
    }
    d2v[t] = d2;
    hi32[t] = (unsigned)(((unsigned long long)__double_as_longlong(d2)) >> 32);
  }
  // bracket: lo = wave min of all keys, hi = wave max of per-lane mins
  unsigned lmin = hi32[0];
#pragma unroll
  for (int t = 1; t < 16; ++t) lmin = min(lmin, hi32[t]);
  unsigned glo = lmin, ghi = lmin;
#pragma unroll
  for (int o = 32; o > 0; o >>= 1){
    glo = min(glo, (unsigned)__shfl_xor((int)glo, o));
    ghi = max(ghi, (unsigned)__shfl_xor((int)ghi, o));
  }
  unsigned lo = glo, hi = ghi;
  while (lo < hi){
    unsigned mid = lo + ((hi - lo) >> 1);
    int c = 0;
#pragma unroll
    for (int t = 0; t < 16; ++t) c += __popcll(__ballot(hi32[t] <= mid));
    if (c >= KK) hi = mid; else lo = mid + 1;
  }
  unsigned H = lo;
  int cLE = 0;
#pragma unroll
  for (int t = 0; t < 16; ++t) cLE += __popcll(__ballot(hi32[t] <= H));
  bool two = (cLE > KK);
  unsigned L = 0xFFFFFFFFu;
  if (two){
    int c_lt = 0;
#pragma unroll
    for (int t = 0; t < 16; ++t) c_lt += __popcll(__ballot(hi32[t] < H));
    int r = KK - c_lt;
    unsigned lo2 = 0u, hi2 = 0xFFFFFFFFu;
    while (lo2 < hi2){
      unsigned mid = lo2 + ((hi2 - lo2) >> 1);
      int c = 0;
#pragma unroll
      for (int t = 0; t < 16; ++t){
        unsigned l32 = (unsigned)((unsigned long long)__double_as_longlong(d2v[t]));
        c += __popcll(__ballot(hi32[t] == H && l32 <= mid));
      }
      if (c >= r) hi2 = mid; else lo2 = mid + 1;
    }
    L = lo2;
  }
  // enumerate selected -> LDS list (global index + weight)
  unsigned long long lml = (1ull << lane) - 1ull;
  int cnt = 0;
#pragma unroll
  for (int t = 0; t < 16; ++t){
    bool sel;
    if (two){
      unsigned l32 = (unsigned)((unsigned long long)__double_as_longlong(d2v[t]));
      sel = (hi32[t] < H) || (hi32[t] == H && l32 <= L);
    } else {
      sel = (hi32[t] <= H);
    }
    unsigned long long m = __ballot(sel);
    if (sel){
      int pos = cnt + __popcll(m & lml);
      if (pos < 48){
        lds_j[wid][pos] = base + lane + 64*t;
        lds_w[wid][pos] = expf(-10.f * (float)d2v[t]);
      }
    }
    cnt += __popcll(m);
  }
  if (cnt > 48) cnt = 48;
  // gather: wave halves process 2 selected neighbors per iteration
  int half = lane >> 5, ch = lane & 31;
  float accm = 0.f, accx = -__builtin_inff();
  int nit = (cnt + 1) >> 1;
  for (int it = 0; it < nit; ++it){
    int si = 2*it + half;
    if (si < cnt){
      int j = lds_j[wid][si];
      float wgt = lds_w[wid][si];
      float fv = fp[(size_t)j*DD + ch];
      float m = wgt * fv;
      accm += m;
      accx = fmaxf(accx, m);
    }
  }
  accm += __shfl_xor(accm, 32);
  accx = fmaxf(accx, __shfl_xor(accx, 32));
  if (lane < DD){
    ap[(size_t)n*64 + lane]      = accm * (1.f/KK);
    ap[(size_t)n*64 + DD + lane] = accx;
  }
}

// fused: xgn (in registers) + post-MLP + BN2 partials
__global__ __launch_bounds__(128) void k_post(
    const float* __restrict__ o1w, const float* __restrict__ o2w,
    const float* __restrict__ o2b,
    const float* __restrict__ p1w, const float* __restrict__ p1b,
    const float* __restrict__ p2w, const float* __restrict__ p2b,
    char* __restrict__ ws)
{
  __shared__ float l1[DD*DD], l2[2*DD*DD], lp1[67*DD], lp2[DD*DD];
  __shared__ float l2b[DD], lp1b[DD], lp2b[DD];
  __shared__ double wpart[2][64];
  int tid = threadIdx.x;
  for (int i = tid; i < DD*DD; i += 128) l1[i] = o1w[i];
  for (int i = tid; i < 2*DD*DD; i += 128) l2[i] = o2w[i];
  for (int i = tid; i < 67*DD; i += 128) lp1[i] = p1w[i];
  for (int i = tid; i < DD*DD; i += 128) lp2[i] = p2w[i];
  if (tid < DD){ l2b[tid] = o2b[tid]; lp1b[tid] = p1b[tid]; lp2b[tid] = p2b[tid]; }
  __syncthreads();
  int node = blockIdx.x*128 + tid;
  const double* hT = (const double*)(ws + OB_H64);
  float hv[DD];
#pragma unroll 4
  for (int c = 0; c < DD; ++c) hv[c] = (float)hT[(size_t)c*NN + node];
  float xg[DD];
#pragma unroll
  for (int c = 0; c < DD; ++c) xg[c] = l2b[c];
#pragma unroll 4
  for (int k = 0; k < DD; ++k){
    float hk = hv[k];
#pragma unroll
    for (int c = 0; c < DD; ++c) xg[c] = fmaf(hk, l1[k*DD+c], xg[c]);
  }
  const float4* ar = (const float4*)(ws + OB_A32) + (size_t)node*16;
#pragma unroll 2
  for (int k4 = 0; k4 < 16; ++k4){
    float4 a = ar[k4];
    float as[4] = {a.x, a.y, a.z, a.w};
#pragma unroll
    for (int u = 0; u < 4; ++u){
      int k = k4*4 + u;
#pragma unroll
      for (int c = 0; c < DD; ++c) xg[c] = fmaf(as[u], l2[k*DD+c], xg[c]);
    }
  }
  float t1[DD];
#pragma unroll
  for (int c = 0; c < DD; ++c) t1[c] = lp1b[c];
#pragma unroll 4
  for (int k = 0; k < DD; ++k){
    float v = xg[k];
#pragma unroll
    for (int c = 0; c < DD; ++c) t1[c] = fmaf(v, lp1[k*DD+c], t1[c]);
  }
  {
    const double* sT = (const double*)(ws + OB_S64);
    float s0 = (float)sT[node], s1 = (float)sT[NN+node], s2 = (float)sT[2*NN+node];
#pragma unroll
    for (int c = 0; c < DD; ++c){
      t1[c] = fmaf(s0, lp1[32*DD+c], t1[c]);
      t1[c] = fmaf(s1, lp1[33*DD+c], t1[c]);
      t1[c] = fmaf(s2, lp1[34*DD+c], t1[c]);
    }
  }
#pragma unroll 4
  for (int k = 0; k < DD; ++k){
    float v = hv[k];
#pragma unroll
    for (int c = 0; c < DD; ++c) t1[c] = fmaf(v, lp1[(35+k)*DD+c], t1[c]);
  }
#pragma unroll
  for (int c = 0; c < DD; ++c) t1[c] = eluf(t1[c]);
  float t2[DD];
#pragma unroll
  for (int c = 0; c < DD; ++c) t2[c] = lp2b[c];
#pragma unroll 4
  for (int k = 0; k < DD; ++k){
    float v = t1[k];
#pragma unroll
    for (int c = 0; c < DD; ++c) t2[c] = fmaf(v, lp2[k*DD+c], t2[c]);
  }
#pragma unroll
  for (int c = 0; c < DD; ++c) t2[c] = eluf(t2[c]);
  float* tr = (float*)(ws + OB_F32) + (size_t)node*DD;
#pragma unroll
  for (int i = 0; i < DD; ++i) tr[i] = t2[i];

  // BN2 partials (f64)
  int lane = tid & 63, wid = tid >> 6;
#pragma unroll
  for (int hlf = 0; hlf < 2; ++hlf){
    double s[16], q[16];
#pragma unroll
    for (int i = 0; i < 16; ++i){ double xv = (double)t2[hlf*16 + i]; s[i] = xv; q[i] = xv*xv; }
#pragma unroll
    for (int o = 32; o > 0; o >>= 1){
#pragma unroll
      for (int i = 0; i < 16; ++i){ s[i] += __shfl_xor(s[i], o); q[i] += __shfl_xor(q[i], o); }
    }
    if (lane == 0){
#pragma unroll
      for (int i = 0; i < 16; ++i){
        wpart[wid][hlf*16 + i] = s[i];
        wpart[wid][32 + hlf*16 + i] = q[i];
      }
    }
  }
  __syncthreads();
  if (tid < 64)
    ((double*)(ws + OB_P2))[blockIdx.x*64 + tid] = wpart[0][tid] + wpart[1][tid];
}

// BN2 finalize (redundant per block) + apply + write out
__global__ __launch_bounds__(128) void k_bnout(
    const float* __restrict__ g, const float* __restrict__ b,
    const char* __restrict__ ws, float* __restrict__ out)
{
  __shared__ double sums[2][64], ltot[64];
  __shared__ float lstat[64], lg[DD], lb[DD];
  int tid = threadIdx.x;
  {
    const double* P2 = (const double*)(ws + OB_P2);
    int comp = tid & 63, grp = tid >> 6;
    double a = 0.0;
    for (int bb = grp; bb < NP2; bb += 2) a += P2[bb*64 + comp];
    sums[grp][comp] = a;
  }
  if (tid < DD){ lg[tid] = g[tid]; lb[tid] = b[tid]; }
  __syncthreads();
  if (tid < 64) ltot[tid] = sums[0][tid] + sums[1][tid];
  __syncthreads();
  if (tid < 32){
    double m = ltot[tid] / (double)NN;
    double qq = ltot[32+tid] / (double)NN;
    lstat[tid] = (float)m;
    lstat[32+tid] = (float)(1.0 / sqrt(qq - m*m + EPSV));
  }
  __syncthreads();
  int node = blockIdx.x*128 + tid;
  const float* tr = (const float*)(ws + OB_F32) + (size_t)node*DD;
  float* orow = out + (size_t)node*DD;
#pragma unroll
  for (int c = 0; c < DD; ++c)
    orow[c] = (tr[c] - lstat[c]) * lstat[32+c] * lg[c] + lb[c];
}

extern "C" void kernel_launch(void* const* d_in, const int* in_sizes, int n_in,
                              void* d_out, int out_size, void* d_ws, size_t ws_size,
                              hipStream_t stream)
{
  const float* x       = (const float*)d_in[0];
  const float* pre_w1  = (const float*)d_in[3];
  const float* pre_b1  = (const float*)d_in[4];
  const float* pre_w2  = (const float*)d_in[5];
  const float* pre_b2  = (const float*)d_in[6];
  const float* bn1_g   = (const float*)d_in[7];
  const float* bn1_b   = (const float*)d_in[8];
  const float* lin_s_w = (const float*)d_in[9];
  const float* lin_s_b = (const float*)d_in[10];
  const float* lin_h_w = (const float*)d_in[11];
  const float* lin_h_b = (const float*)d_in[12];
  const float* out1_w  = (const float*)d_in[13];
  const float* out2_w  = (const float*)d_in[14];
  const float* out2_b  = (const float*)d_in[15];
  const float* post_w1 = (const float*)d_in[16];
  const float* post_b1 = (const float*)d_in[17];
  const float* post_w2 = (const float*)d_in[18];
  const float* post_b2 = (const float*)d_in[19];
  const float* bn2_g   = (const float*)d_in[20];
  const float* bn2_b   = (const float*)d_in[21];
  char* ws  = (char*)d_ws;
  float* out = (float*)d_out;

  k_pre  <<<500, 128, 0, stream>>>(x, pre_w1, pre_b1, pre_w2, pre_b2, ws);
  k_sfeat<<<250, 128, 0, stream>>>(lin_s_w, lin_s_b, lin_h_w, lin_h_b, bn1_g, bn1_b, ws);
  k_knn  <<<8000, 256, 0, stream>>>(ws);
  k_post <<<250, 128, 0, stream>>>(out1_w, out2_w, out2_b, post_w1, post_b1,
                                   post_w2, post_b2, ws);
  k_bnout<<<250, 128, 0, stream>>>(bn2_g, bn2_b, ws, out);
}